// Round 2
// baseline (476.156 us; speedup 1.0000x reference)
//
#include <hip/hip_runtime.h>
#include <math.h>

#define DUR 32
#define DIM 256
#define TT  528   // sum_b (32-b)

// ws float layout — total 2176 floats, within the 2304-float envelope the
// previous session's passing kernel already used.
#define WS_BSUM 0       // [32]   branch sums
#define WS_BSQ  32      // [32]   branch sumsq
#define WS_CY   64      // [528]  column sums of g*lnw
#define WS_CW   592     // [528]  sum_o lnw
#define WS_CB   1120    // [528]  sum_o lnb
#define WS_S    1648    // [528]  in-proj row sums
#define WS_ZERO_FLOATS 592   // BSUM+BSQ+CY

__device__ __forceinline__ float gelu_exact(float v) {
    return 0.5f * v * (1.0f + erff(v * 0.70710678118654752f));
}

__device__ __forceinline__ float wave_reduce_down(float v) {
    v += __shfl_down(v, 32, 64);
    v += __shfl_down(v, 16, 64);
    v += __shfl_down(v, 8, 64);
    v += __shfl_down(v, 4, 64);
    v += __shfl_down(v, 2, 64);
    v += __shfl_down(v, 1, 64);
    return v;   // lane 0 holds the sum
}

// CW/CB column sums over o (independent of conv output). 528 blocks.
__global__ __launch_bounds__(256) void prep_kernel(
    const float* __restrict__ lnw, const float* __restrict__ lnb,
    float* __restrict__ ws)
{
    const int bid = blockIdx.x;
    const int n = threadIdx.x;
    // map global t index -> (branch b, position t)
    int b = 0, off = 0;
    while (bid >= off + (DUR - b)) { off += DUR - b; ++b; }
    const int t = bid - off;
    const float lw = lnw[((size_t)(b * DIM + n)) * DUR + t];
    const float lb = lnb[((size_t)(b * DIM + n)) * DUR + t];
    __shared__ float rw[4], rb[4];
    const int wave = n >> 6, lane = n & 63;
    const float a = wave_reduce_down(lw);
    const float c = wave_reduce_down(lb);
    if (lane == 0) { rw[wave] = a; rb[wave] = c; }
    __syncthreads();
    if (n == 0) {
        ws[WS_CW + bid] = rw[0] + rw[1] + rw[2] + rw[3];
        ws[WS_CB + bid] = rb[0] + rb[1] + rb[2] + rb[3];
    }
}

// One wave owns one (b, o) pair. No LDS, no barriers.
// Lanes cover input channels in 4 chunks of 64; acc[L] lives in registers.
template<int BB>
__device__ __forceinline__ void wave_body(
    const int o, const int lane,
    const float* __restrict__ x, const float* __restrict__ W,
    const float* __restrict__ convb, const float* __restrict__ lnw,
    float* __restrict__ ws)
{
    constexpr int k  = BB + 1;
    constexpr int L  = DUR - BB;
    constexpr int K4 = (k + 3) / 4;

    const float* Wo = W + (size_t)(BB * DIM + o) * (DIM * DUR);

    float acc[L];
#pragma unroll
    for (int t = 0; t < L; ++t) acc[t] = 0.f;

#pragma unroll 1
    for (int c = 0; c < 4; ++c) {
        const int i = c * 64 + lane;
        // per-lane contiguous W row prefix: K4 float4 quads
        float4 w4[K4];
        const float* Wl = Wo + i * DUR;
#pragma unroll
        for (int m = 0; m < K4; ++m) w4[m] = *(const float4*)(Wl + 4 * m);
        // x column for channel i: per-tau the 64 lanes read 64 consecutive
        // floats -> coalesced; x is 32KB, L2-resident.
        float xv[32];
#pragma unroll
        for (int tau = 0; tau < 32; ++tau) xv[tau] = x[tau * DIM + i];
#pragma unroll
        for (int t = 0; t < L; ++t) {
#pragma unroll
            for (int m = 0; m < K4; ++m) {
                acc[t] = fmaf(xv[t + 4*m + 0], w4[m].x, acc[t]);
                if (4*m + 1 < k) acc[t] = fmaf(xv[t + 4*m + 1], w4[m].y, acc[t]);
                if (4*m + 2 < k) acc[t] = fmaf(xv[t + 4*m + 2], w4[m].z, acc[t]);
                if (4*m + 3 < k) acc[t] = fmaf(xv[t + 4*m + 3], w4[m].w, acc[t]);
            }
        }
    }

    // butterfly-reduce each acc[t] over 64 lanes; lane t keeps total of acc[t]
    float mine = 0.f;
#pragma unroll
    for (int t = 0; t < L; ++t) {
        float v = acc[t];
        v += __shfl_xor(v, 1, 64);
        v += __shfl_xor(v, 2, 64);
        v += __shfl_xor(v, 4, 64);
        v += __shfl_xor(v, 8, 64);
        v += __shfl_xor(v, 16, 64);
        v += __shfl_xor(v, 32, 64);
        if (lane == t) mine = v;
    }

    constexpr int tg = BB * DUR - (BB * (BB - 1)) / 2;
    float g = 0.f;
    if (lane < L) {
        const float y = mine + convb[BB * DIM + o];
        g = gelu_exact(y);
        const float lw = lnw[((size_t)(BB * DIM + o)) * DUR + lane];
        atomicAdd(ws + WS_CY + tg + lane, g * lw);
    }
    const float s1 = wave_reduce_down(g);
    const float s2 = wave_reduce_down(g * g);
    if (lane == 0) {
        atomicAdd(ws + WS_BSUM + BB, s1);
        atomicAdd(ws + WS_BSQ  + BB, s2);
    }
}

__global__ __launch_bounds__(256, 4) void conv_kernel(
    const float* __restrict__ x, const float* __restrict__ W,
    const float* __restrict__ convb, const float* __restrict__ lnw,
    float* __restrict__ ws)
{
    const int q    = blockIdx.x * 4 + (threadIdx.x >> 6);  // global wave id
    const int lane = threadIdx.x & 63;
    const int bb   = 31 - (q & 31);   // cycle classes; heavy-fetch first
    const int o    = q >> 5;
    switch (bb) {
        case  0: wave_body< 0>(o, lane, x, W, convb, lnw, ws); break;
        case  1: wave_body< 1>(o, lane, x, W, convb, lnw, ws); break;
        case  2: wave_body< 2>(o, lane, x, W, convb, lnw, ws); break;
        case  3: wave_body< 3>(o, lane, x, W, convb, lnw, ws); break;
        case  4: wave_body< 4>(o, lane, x, W, convb, lnw, ws); break;
        case  5: wave_body< 5>(o, lane, x, W, convb, lnw, ws); break;
        case  6: wave_body< 6>(o, lane, x, W, convb, lnw, ws); break;
        case  7: wave_body< 7>(o, lane, x, W, convb, lnw, ws); break;
        case  8: wave_body< 8>(o, lane, x, W, convb, lnw, ws); break;
        case  9: wave_body< 9>(o, lane, x, W, convb, lnw, ws); break;
        case 10: wave_body<10>(o, lane, x, W, convb, lnw, ws); break;
        case 11: wave_body<11>(o, lane, x, W, convb, lnw, ws); break;
        case 12: wave_body<12>(o, lane, x, W, convb, lnw, ws); break;
        case 13: wave_body<13>(o, lane, x, W, convb, lnw, ws); break;
        case 14: wave_body<14>(o, lane, x, W, convb, lnw, ws); break;
        case 15: wave_body<15>(o, lane, x, W, convb, lnw, ws); break;
        case 16: wave_body<16>(o, lane, x, W, convb, lnw, ws); break;
        case 17: wave_body<17>(o, lane, x, W, convb, lnw, ws); break;
        case 18: wave_body<18>(o, lane, x, W, convb, lnw, ws); break;
        case 19: wave_body<19>(o, lane, x, W, convb, lnw, ws); break;
        case 20: wave_body<20>(o, lane, x, W, convb, lnw, ws); break;
        case 21: wave_body<21>(o, lane, x, W, convb, lnw, ws); break;
        case 22: wave_body<22>(o, lane, x, W, convb, lnw, ws); break;
        case 23: wave_body<23>(o, lane, x, W, convb, lnw, ws); break;
        case 24: wave_body<24>(o, lane, x, W, convb, lnw, ws); break;
        case 25: wave_body<25>(o, lane, x, W, convb, lnw, ws); break;
        case 26: wave_body<26>(o, lane, x, W, convb, lnw, ws); break;
        case 27: wave_body<27>(o, lane, x, W, convb, lnw, ws); break;
        case 28: wave_body<28>(o, lane, x, W, convb, lnw, ws); break;
        case 29: wave_body<29>(o, lane, x, W, convb, lnw, ws); break;
        case 30: wave_body<30>(o, lane, x, W, convb, lnw, ws); break;
        default: wave_body<31>(o, lane, x, W, convb, lnw, ws); break;
    }
}

// c[t] from LN stats + colsums, then s = Wv @ c + 256*bv. 132 blocks x 4 rows.
__global__ __launch_bounds__(256) void proj1_kernel(
    float* ws, const float* __restrict__ in_proj_w,
    const float* __restrict__ in_proj_b)
{
    __shared__ float cc[TT];
    __shared__ float mu_s[32], r_s[32];
    __shared__ int map[TT];
    const int n = threadIdx.x;
    if (n < 32) {
        const int Lb = 32 - n;
        const float cnt = 256.f * (float)Lb;
        const float mu = ws[WS_BSUM + n] / cnt;
        const float var = ws[WS_BSQ + n] / cnt - mu * mu;
        mu_s[n] = mu;
        r_s[n] = rsqrtf(var + 1e-5f);
        const int off = n * 32 - (n * (n - 1)) / 2;
        for (int t = 0; t < Lb; ++t) map[off + t] = n;
    }
    __syncthreads();
    for (int t = n; t < TT; t += 256) {
        const int b = map[t];
        cc[t] = (ws[WS_CY + t] - mu_s[b] * ws[WS_CW + t]) * r_s[b] + ws[WS_CB + t];
    }
    __syncthreads();
    const int wave = n >> 6, lane = n & 63;
    const int row = blockIdx.x * 4 + wave;
    const float* Wr = in_proj_w + (size_t)(2 * TT + row) * TT;
    float a = 0.f;
    for (int t = lane; t < TT; t += 64) a = fmaf(Wr[t], cc[t], a);
    a = wave_reduce_down(a);
    if (lane == 0) ws[WS_S + row] = a + 256.f * in_proj_b[2 * TT + row];
}

// merged proj2a+proj2b: block w computes its 32 rows u = w*128 + j, then the
// mean, then broadcasts out[w*256 + d]. 4 blocks.
__global__ __launch_bounds__(256) void proj2_kernel(
    const float* __restrict__ ws, const float* __restrict__ out_proj_w,
    const float* __restrict__ out_proj_b, float* __restrict__ out)
{
    const int w = blockIdx.x, n = threadIdx.x;
    const int wave = n >> 6, lane = n & 63;
    __shared__ float s2s[32];
    __shared__ float mv;
    for (int jj = 0; jj < 8; ++jj) {
        const int j = wave * 8 + jj;
        const int u = w * 128 + j;
        const float* Or = out_proj_w + (size_t)u * TT;
        float a = 0.f;
        for (int t = lane; t < TT; t += 64) a = fmaf(Or[t], ws[WS_S + t], a);
        a = wave_reduce_down(a);
        if (lane == 0) s2s[j] = a + 256.f * out_proj_b[u];
    }
    __syncthreads();
    if (n < 64) {
        float v = (n < 32) ? s2s[n] : 0.f;
        v += __shfl_down(v, 16, 64);
        v += __shfl_down(v, 8, 64);
        v += __shfl_down(v, 4, 64);
        v += __shfl_down(v, 2, 64);
        v += __shfl_down(v, 1, 64);
        if (n == 0) mv = v * (1.0f / 32.0f);
    }
    __syncthreads();
    out[w * 256 + n] = mv;
}

extern "C" void kernel_launch(void* const* d_in, const int* in_sizes, int n_in,
                              void* d_out, int out_size, void* d_ws, size_t ws_size,
                              hipStream_t stream)
{
    const float* x   = (const float*)d_in[0];
    const float* W   = (const float*)d_in[1];
    const float* cb  = (const float*)d_in[2];
    const float* lnw = (const float*)d_in[3];
    const float* lnb = (const float*)d_in[4];
    const float* ipw = (const float*)d_in[5];
    const float* ipb = (const float*)d_in[6];
    const float* opw = (const float*)d_in[7];
    const float* opb = (const float*)d_in[8];
    float* ws  = (float*)d_ws;
    float* out = (float*)d_out;

    hipMemsetAsync(ws, 0, WS_ZERO_FLOATS * sizeof(float), stream);
    prep_kernel<<<TT, 256, 0, stream>>>(lnw, lnb, ws);
    conv_kernel<<<2048, 256, 0, stream>>>(x, W, cb, lnw, ws);
    proj1_kernel<<<132, 256, 0, stream>>>(ws, ipw, ipb);
    proj2_kernel<<<4, 256, 0, stream>>>(ws, opw, opb, out);
}

// Round 3
// 451.810 us; speedup vs baseline: 1.0539x; 1.0539x over previous
//
#include <hip/hip_runtime.h>
#include <math.h>

#define DUR 32
#define DIM 256
#define TT  528   // sum_b (32-b)

// ws float layout — total 2176 floats (within the proven 2304-float envelope)
#define WS_BSUM 0       // [32]   branch sums
#define WS_BSQ  32      // [32]   branch sumsq
#define WS_CY   64      // [528]  column sums of g*lnw
#define WS_CW   592     // [528]  sum_o lnw
#define WS_CB   1120    // [528]  sum_o lnb
#define WS_S    1648    // [528]  in-proj row sums
#define WS_ZERO_FLOATS 592   // BSUM+BSQ+CY

__device__ __forceinline__ float gelu_exact(float v) {
    return 0.5f * v * (1.0f + erff(v * 0.70710678118654752f));
}

__device__ __forceinline__ float wave_reduce_down(float v) {
    v += __shfl_down(v, 32, 64);
    v += __shfl_down(v, 16, 64);
    v += __shfl_down(v, 8, 64);
    v += __shfl_down(v, 4, 64);
    v += __shfl_down(v, 2, 64);
    v += __shfl_down(v, 1, 64);
    return v;   // lane 0 holds the sum
}

// One wave owns one (b, o) pair. No LDS, no barriers.
// W chunk loads are register double-buffered; xv and W quads are pinned in
// VGPRs via empty asm so the compiler cannot sink/remat the loads into the
// FMA consumers (round-2 failure mode: VGPR=52, VALUBusy=7%).
template<int BB>
__device__ __forceinline__ void wave_body(
    const int o, const int lane,
    const float* __restrict__ x, const float* __restrict__ W,
    const float* __restrict__ convb, const float* __restrict__ lnw,
    float* __restrict__ ws)
{
    constexpr int k  = BB + 1;
    constexpr int L  = DUR - BB;
    constexpr int K4 = (k + 3) / 4;

    const float* Wo = W + (size_t)(BB * DIM + o) * (DIM * DUR);

    float4 wbuf[2][K4];
    {   // issue chunk 0 W loads
        const float* Wl = Wo + (size_t)lane * DUR;
#pragma unroll
        for (int m = 0; m < K4; ++m) wbuf[0][m] = *(const float4*)(Wl + 4 * m);
    }

    float acc[L];
#pragma unroll
    for (int t = 0; t < L; ++t) acc[t] = 0.f;

#pragma unroll
    for (int c = 0; c < 4; ++c) {
        const int cur = c & 1, nxt = cur ^ 1;
        if (c < 3) {   // issue next chunk's W loads (stays in flight under compute)
            const float* Wl = Wo + (size_t)((c + 1) * 64 + lane) * DUR;
#pragma unroll
            for (int m = 0; m < K4; ++m) wbuf[nxt][m] = *(const float4*)(Wl + 4 * m);
        }
        // x column for channel i: per-tau the 64 lanes read 256 consecutive
        // bytes (coalesced); x is 32KB, L2-resident.
        const int i = c * 64 + lane;
        float xv[32];
#pragma unroll
        for (int tau = 0; tau < 32; ++tau) xv[tau] = x[tau * DIM + i];
        // pin xv and current W quads in registers
#pragma unroll
        for (int tau = 0; tau < 32; ++tau) asm volatile("" : "+v"(xv[tau]));
#pragma unroll
        for (int m = 0; m < K4; ++m) {
            asm volatile("" : "+v"(wbuf[cur][m].x), "+v"(wbuf[cur][m].y),
                              "+v"(wbuf[cur][m].z), "+v"(wbuf[cur][m].w));
        }
#pragma unroll
        for (int t = 0; t < L; ++t) {
#pragma unroll
            for (int m = 0; m < K4; ++m) {
                acc[t] = fmaf(xv[t + 4*m + 0], wbuf[cur][m].x, acc[t]);
                if (4*m + 1 < k) acc[t] = fmaf(xv[t + 4*m + 1], wbuf[cur][m].y, acc[t]);
                if (4*m + 2 < k) acc[t] = fmaf(xv[t + 4*m + 2], wbuf[cur][m].z, acc[t]);
                if (4*m + 3 < k) acc[t] = fmaf(xv[t + 4*m + 3], wbuf[cur][m].w, acc[t]);
            }
        }
    }

    // butterfly-reduce each acc[t] over 64 lanes; lane t keeps total of acc[t]
    float mine = 0.f;
#pragma unroll
    for (int t = 0; t < L; ++t) {
        float v = acc[t];
        v += __shfl_xor(v, 1, 64);
        v += __shfl_xor(v, 2, 64);
        v += __shfl_xor(v, 4, 64);
        v += __shfl_xor(v, 8, 64);
        v += __shfl_xor(v, 16, 64);
        v += __shfl_xor(v, 32, 64);
        if (lane == t) mine = v;
    }

    constexpr int tg = BB * DUR - (BB * (BB - 1)) / 2;
    float g = 0.f;
    if (lane < L) {
        const float y = mine + convb[BB * DIM + o];
        g = gelu_exact(y);
        const float lw = lnw[((size_t)(BB * DIM + o)) * DUR + lane];
        atomicAdd(ws + WS_CY + tg + lane, g * lw);
    }
    const float s1 = wave_reduce_down(g);
    const float s2 = wave_reduce_down(g * g);
    if (lane == 0) {
        atomicAdd(ws + WS_BSUM + BB, s1);
        atomicAdd(ws + WS_BSQ  + BB, s2);
    }
}

// blocks [0,2048): conv, block-uniform class, 4 o's per block (one per wave).
// blocks [2048, 2048+528): CW/CB column sums (only needed by proj1; scheduled
// last so they fill the conv tail).
__global__ __launch_bounds__(256, 4) void conv_kernel(
    const float* __restrict__ x, const float* __restrict__ W,
    const float* __restrict__ convb, const float* __restrict__ lnw,
    const float* __restrict__ lnb, float* __restrict__ ws)
{
    const int bid = blockIdx.x;
    const int n = threadIdx.x;
    if (bid >= 2048) {
        const int pb = bid - 2048;          // 0..527
        int b = 0, off = 0;
        while (pb >= off + (DUR - b)) { off += DUR - b; ++b; }
        const int t = pb - off;
        const float lw = lnw[((size_t)(b * DIM + n)) * DUR + t];
        const float lb = lnb[((size_t)(b * DIM + n)) * DUR + t];
        __shared__ float rw[4], rb[4];
        const int wave = n >> 6, lane = n & 63;
        const float a = wave_reduce_down(lw);
        const float c = wave_reduce_down(lb);
        if (lane == 0) { rw[wave] = a; rb[wave] = c; }
        __syncthreads();
        if (n == 0) {
            ws[WS_CW + pb] = rw[0] + rw[1] + rw[2] + rw[3];
            ws[WS_CB + pb] = rb[0] + rb[1] + rb[2] + rb[3];
        }
        return;
    }

    // class scramble: within each 32-bid og-block it's a permutation (13 odd),
    // and a CU's resident blocks (bid = cu + 256*j) get well-spread classes.
    const int bb   = (13 * ((bid & 31) + (bid >> 8))) & 31;
    const int o    = (bid >> 5) * 4 + (n >> 6);
    const int lane = n & 63;
    switch (bb) {
        case  0: wave_body< 0>(o, lane, x, W, convb, lnw, ws); break;
        case  1: wave_body< 1>(o, lane, x, W, convb, lnw, ws); break;
        case  2: wave_body< 2>(o, lane, x, W, convb, lnw, ws); break;
        case  3: wave_body< 3>(o, lane, x, W, convb, lnw, ws); break;
        case  4: wave_body< 4>(o, lane, x, W, convb, lnw, ws); break;
        case  5: wave_body< 5>(o, lane, x, W, convb, lnw, ws); break;
        case  6: wave_body< 6>(o, lane, x, W, convb, lnw, ws); break;
        case  7: wave_body< 7>(o, lane, x, W, convb, lnw, ws); break;
        case  8: wave_body< 8>(o, lane, x, W, convb, lnw, ws); break;
        case  9: wave_body< 9>(o, lane, x, W, convb, lnw, ws); break;
        case 10: wave_body<10>(o, lane, x, W, convb, lnw, ws); break;
        case 11: wave_body<11>(o, lane, x, W, convb, lnw, ws); break;
        case 12: wave_body<12>(o, lane, x, W, convb, lnw, ws); break;
        case 13: wave_body<13>(o, lane, x, W, convb, lnw, ws); break;
        case 14: wave_body<14>(o, lane, x, W, convb, lnw, ws); break;
        case 15: wave_body<15>(o, lane, x, W, convb, lnw, ws); break;
        case 16: wave_body<16>(o, lane, x, W, convb, lnw, ws); break;
        case 17: wave_body<17>(o, lane, x, W, convb, lnw, ws); break;
        case 18: wave_body<18>(o, lane, x, W, convb, lnw, ws); break;
        case 19: wave_body<19>(o, lane, x, W, convb, lnw, ws); break;
        case 20: wave_body<20>(o, lane, x, W, convb, lnw, ws); break;
        case 21: wave_body<21>(o, lane, x, W, convb, lnw, ws); break;
        case 22: wave_body<22>(o, lane, x, W, convb, lnw, ws); break;
        case 23: wave_body<23>(o, lane, x, W, convb, lnw, ws); break;
        case 24: wave_body<24>(o, lane, x, W, convb, lnw, ws); break;
        case 25: wave_body<25>(o, lane, x, W, convb, lnw, ws); break;
        case 26: wave_body<26>(o, lane, x, W, convb, lnw, ws); break;
        case 27: wave_body<27>(o, lane, x, W, convb, lnw, ws); break;
        case 28: wave_body<28>(o, lane, x, W, convb, lnw, ws); break;
        case 29: wave_body<29>(o, lane, x, W, convb, lnw, ws); break;
        case 30: wave_body<30>(o, lane, x, W, convb, lnw, ws); break;
        default: wave_body<31>(o, lane, x, W, convb, lnw, ws); break;
    }
}

// c[t] from LN stats + colsums, then s = Wv @ c + 256*bv. 132 blocks x 4 rows.
__global__ __launch_bounds__(256) void proj1_kernel(
    float* ws, const float* __restrict__ in_proj_w,
    const float* __restrict__ in_proj_b)
{
    __shared__ float cc[TT];
    __shared__ float mu_s[32], r_s[32];
    __shared__ int map[TT];
    const int n = threadIdx.x;
    if (n < 32) {
        const int Lb = 32 - n;
        const float cnt = 256.f * (float)Lb;
        const float mu = ws[WS_BSUM + n] / cnt;
        const float var = ws[WS_BSQ + n] / cnt - mu * mu;
        mu_s[n] = mu;
        r_s[n] = rsqrtf(var + 1e-5f);
        const int off = n * 32 - (n * (n - 1)) / 2;
        for (int t = 0; t < Lb; ++t) map[off + t] = n;
    }
    __syncthreads();
    for (int t = n; t < TT; t += 256) {
        const int b = map[t];
        cc[t] = (ws[WS_CY + t] - mu_s[b] * ws[WS_CW + t]) * r_s[b] + ws[WS_CB + t];
    }
    __syncthreads();
    const int wave = n >> 6, lane = n & 63;
    const int row = blockIdx.x * 4 + wave;
    const float* Wr = in_proj_w + (size_t)(2 * TT + row) * TT;
    float a = 0.f;
    for (int t = lane; t < TT; t += 64) a = fmaf(Wr[t], cc[t], a);
    a = wave_reduce_down(a);
    if (lane == 0) ws[WS_S + row] = a + 256.f * in_proj_b[2 * TT + row];
}

// merged proj2a+proj2b: block w computes its 32 rows u = w*128 + j, then the
// mean, then broadcasts out[w*256 + d]. 4 blocks.
__global__ __launch_bounds__(256) void proj2_kernel(
    const float* __restrict__ ws, const float* __restrict__ out_proj_w,
    const float* __restrict__ out_proj_b, float* __restrict__ out)
{
    const int w = blockIdx.x, n = threadIdx.x;
    const int wave = n >> 6, lane = n & 63;
    __shared__ float s2s[32];
    __shared__ float mv;
    for (int jj = 0; jj < 8; ++jj) {
        const int j = wave * 8 + jj;
        const int u = w * 128 + j;
        const float* Or = out_proj_w + (size_t)u * TT;
        float a = 0.f;
        for (int t = lane; t < TT; t += 64) a = fmaf(Or[t], ws[WS_S + t], a);
        a = wave_reduce_down(a);
        if (lane == 0) s2s[j] = a + 256.f * out_proj_b[u];
    }
    __syncthreads();
    if (n < 64) {
        float v = (n < 32) ? s2s[n] : 0.f;
        v += __shfl_down(v, 16, 64);
        v += __shfl_down(v, 8, 64);
        v += __shfl_down(v, 4, 64);
        v += __shfl_down(v, 2, 64);
        v += __shfl_down(v, 1, 64);
        if (n == 0) mv = v * (1.0f / 32.0f);
    }
    __syncthreads();
    out[w * 256 + n] = mv;
}

extern "C" void kernel_launch(void* const* d_in, const int* in_sizes, int n_in,
                              void* d_out, int out_size, void* d_ws, size_t ws_size,
                              hipStream_t stream)
{
    const float* x   = (const float*)d_in[0];
    const float* W   = (const float*)d_in[1];
    const float* cb  = (const float*)d_in[2];
    const float* lnw = (const float*)d_in[3];
    const float* lnb = (const float*)d_in[4];
    const float* ipw = (const float*)d_in[5];
    const float* ipb = (const float*)d_in[6];
    const float* opw = (const float*)d_in[7];
    const float* opb = (const float*)d_in[8];
    float* ws  = (float*)d_ws;
    float* out = (float*)d_out;

    hipMemsetAsync(ws, 0, WS_ZERO_FLOATS * sizeof(float), stream);
    conv_kernel<<<2048 + TT, 256, 0, stream>>>(x, W, cb, lnw, lnb, ws);
    proj1_kernel<<<132, 256, 0, stream>>>(ws, ipw, ipb);
    proj2_kernel<<<4, 256, 0, stream>>>(ws, opw, opb, out);
}